// Round 1
// baseline (3515.559 us; speedup 1.0000x reference)
//
#include <hip/hip_runtime.h>
#include <hip/hip_bf16.h>
#include <stdint.h>

// Problem constants (match reference)
#define N_PTS    32768
#define N_CLU    2048
#define DIM      512
#define DECAY    0.99f
#define EPS      1e-5f
#define NORM_EPS 1e-12f

// Output layout (flat f32, reference return order)
#define OUT_Q      0                          // quantized [N_PTS*DIM]
#define OUT_IDX    (N_PTS*DIM)                // indices   [N_PTS]
#define OUT_NEWC   (OUT_IDX + N_PTS)          // new_centroids [N_CLU*DIM]
#define OUT_SIZE   (OUT_NEWC + N_CLU*DIM)     // new_size  [N_CLU]
#define OUT_NEWW   (OUT_SIZE + N_CLU)         // new_w     [N_CLU*DIM]

// ---------------- init workspace ----------------
__global__ void init_kernel(unsigned long long* __restrict__ best,
                            int* __restrict__ counts,
                            float* __restrict__ dw) {
    int i = blockIdx.x * blockDim.x + threadIdx.x;
    int stride = gridDim.x * blockDim.x;
    for (int j = i; j < N_PTS; j += stride) best[j] = 0xFFFFFFFFFFFFFFFFULL;
    for (int j = i; j < N_CLU; j += stride) counts[j] = 0;
    for (int j = i; j < N_CLU * DIM; j += stride) dw[j] = 0.0f;
}

// ---------------- row 1/norm of X (one wave per row) ----------------
__global__ void rownorm_kernel(const float* __restrict__ X,
                               float* __restrict__ rnorm) {
    int wave = (blockIdx.x * blockDim.x + threadIdx.x) >> 6;
    int lane = threadIdx.x & 63;
    if (wave >= N_PTS) return;
    const float4* xr = (const float4*)(X + (size_t)wave * DIM);
    float4 a = xr[lane];
    float4 b = xr[lane + 64];
    float ss = a.x*a.x + a.y*a.y + a.z*a.z + a.w*a.w
             + b.x*b.x + b.y*b.y + b.z*b.z + b.w*b.w;
    #pragma unroll
    for (int off = 32; off > 0; off >>= 1) ss += __shfl_xor(ss, off);
    if (lane == 0) rnorm[wave] = 1.0f / fmaxf(sqrtf(ss), NORM_EPS);
}

// ---------------- |c_k|^2 (one wave per centroid) ----------------
__global__ void cnorm_kernel(const float* __restrict__ C,
                             float* __restrict__ cnorm2) {
    int wave = (blockIdx.x * blockDim.x + threadIdx.x) >> 6;
    int lane = threadIdx.x & 63;
    if (wave >= N_CLU) return;
    const float4* cr = (const float4*)(C + (size_t)wave * DIM);
    float4 a = cr[lane];
    float4 b = cr[lane + 64];
    float ss = a.x*a.x + a.y*a.y + a.z*a.z + a.w*a.w
             + b.x*b.x + b.y*b.y + b.z*b.z + b.w*b.w;
    #pragma unroll
    for (int off = 32; off > 0; off >>= 1) ss += __shfl_xor(ss, off);
    if (lane == 0) cnorm2[wave] = ss;
}

// ---------------- fused fp32 GEMM + per-row argmin ----------------
// score[i][k] = |c_k|^2 - 2 * (Xn_i . c_k); argmin_k matches the reference
// distance argmin (|xn|^2 row-constant dropped). 128x128 tile, BK=16,
// 256 threads, 8x8 microtile. Per-row winner combined across N-tiles via
// u64 atomicMin on (order-encoded score << 32 | idx) — ties -> smallest idx,
// matching jnp.argmin.
#define BM 128
#define BN 128
#define BK 16

__global__ __launch_bounds__(256) void dist_argmin_kernel(
    const float* __restrict__ X, const float* __restrict__ C,
    const float* __restrict__ rnorm, const float* __restrict__ cnorm2,
    unsigned long long* __restrict__ best) {
    __shared__ float As[BK][BM];   // K-major
    __shared__ float Bs[BK][BN];

    const int tid = threadIdx.x;
    const int tx = tid & 15;
    const int ty = tid >> 4;
    const int m0 = blockIdx.x * BM;
    const int n0 = blockIdx.y * BN;

    // staging assignment is tid-invariant across k-chunks
    const int f0 = tid;         // float4 slot 0..255
    const int f1 = tid + 256;   // 256..511
    const int rowA0 = f0 >> 2, kq0 = f0 & 3;
    const int rowA1 = f1 >> 2, kq1 = f1 & 3;
    const float rs0 = rnorm[m0 + rowA0];
    const float rs1 = rnorm[m0 + rowA1];
    const float* Abase0 = X + (size_t)(m0 + rowA0) * DIM + kq0 * 4;
    const float* Abase1 = X + (size_t)(m0 + rowA1) * DIM + kq1 * 4;
    const float* Bbase0 = C + (size_t)(n0 + rowA0) * DIM + kq0 * 4;
    const float* Bbase1 = C + (size_t)(n0 + rowA1) * DIM + kq1 * 4;

    float acc[8][8];
    #pragma unroll
    for (int r = 0; r < 8; r++)
        #pragma unroll
        for (int c = 0; c < 8; c++) acc[r][c] = 0.0f;

    for (int c0 = 0; c0 < DIM; c0 += BK) {
        float4 va0 = *(const float4*)(Abase0 + c0);
        float4 va1 = *(const float4*)(Abase1 + c0);
        float4 vb0 = *(const float4*)(Bbase0 + c0);
        float4 vb1 = *(const float4*)(Bbase1 + c0);
        As[kq0*4+0][rowA0] = va0.x*rs0; As[kq0*4+1][rowA0] = va0.y*rs0;
        As[kq0*4+2][rowA0] = va0.z*rs0; As[kq0*4+3][rowA0] = va0.w*rs0;
        As[kq1*4+0][rowA1] = va1.x*rs1; As[kq1*4+1][rowA1] = va1.y*rs1;
        As[kq1*4+2][rowA1] = va1.z*rs1; As[kq1*4+3][rowA1] = va1.w*rs1;
        Bs[kq0*4+0][rowA0] = vb0.x; Bs[kq0*4+1][rowA0] = vb0.y;
        Bs[kq0*4+2][rowA0] = vb0.z; Bs[kq0*4+3][rowA0] = vb0.w;
        Bs[kq1*4+0][rowA1] = vb1.x; Bs[kq1*4+1][rowA1] = vb1.y;
        Bs[kq1*4+2][rowA1] = vb1.z; Bs[kq1*4+3][rowA1] = vb1.w;
        __syncthreads();

        #pragma unroll
        for (int t = 0; t < BK; t++) {
            float4 a0 = *(const float4*)&As[t][ty * 8];
            float4 a1 = *(const float4*)&As[t][ty * 8 + 4];
            float4 b0 = *(const float4*)&Bs[t][tx * 8];
            float4 b1 = *(const float4*)&Bs[t][tx * 8 + 4];
            float a[8] = {a0.x, a0.y, a0.z, a0.w, a1.x, a1.y, a1.z, a1.w};
            float b[8] = {b0.x, b0.y, b0.z, b0.w, b1.x, b1.y, b1.z, b1.w};
            #pragma unroll
            for (int r = 0; r < 8; r++)
                #pragma unroll
                for (int c = 0; c < 8; c++)
                    acc[r][c] = fmaf(a[r], b[c], acc[r][c]);
        }
        __syncthreads();
    }

    // epilogue: per-row argmin over this block's 128 columns
    #pragma unroll
    for (int r = 0; r < 8; r++) {
        float bs = INFINITY;
        int bi = 0x7FFFFFFF;
        #pragma unroll
        for (int c = 0; c < 8; c++) {
            int gc = n0 + tx * 8 + c;
            float s = cnorm2[gc] - 2.0f * acc[r][c];
            if (s < bs) { bs = s; bi = gc; }   // ascending c: first wins ties
        }
        unsigned u = __float_as_uint(bs);
        u = (u & 0x80000000u) ? ~u : (u | 0x80000000u);  // order-preserving
        unsigned long long p = ((unsigned long long)u << 32) | (unsigned)bi;
        #pragma unroll
        for (int off = 1; off < 16; off <<= 1) {
            unsigned long long q = __shfl_xor(p, off);
            if (q < p) p = q;
        }
        if (tx == 0) atomicMin(best + m0 + ty * 8 + r, p);
    }
}

// ---------------- decode winners, histogram ----------------
__global__ void decode_kernel(const unsigned long long* __restrict__ best,
                              int* __restrict__ idxs,
                              float* __restrict__ out_idx,
                              int* __restrict__ counts) {
    int i = blockIdx.x * blockDim.x + threadIdx.x;
    if (i >= N_PTS) return;
    int idx = (int)(unsigned)(best[i] & 0xFFFFFFFFu);
    idxs[i] = idx;
    out_idx[i] = (float)idx;
    atomicAdd(&counts[idx], 1);
}

// ---------------- quantized = centroids[idx] (one wave per row) ----------------
__global__ void quant_kernel(const float* __restrict__ C,
                             const int* __restrict__ idxs,
                             float* __restrict__ outq) {
    int wave = (blockIdx.x * blockDim.x + threadIdx.x) >> 6;
    int lane = threadIdx.x & 63;
    if (wave >= N_PTS) return;
    int idx = idxs[wave];
    const float4* src = (const float4*)(C + (size_t)idx * DIM);
    float4* dst = (float4*)(outq + (size_t)wave * DIM);
    dst[lane] = src[lane];
    dst[lane + 64] = src[lane + 64];
}

// ---------------- dw scatter-sum of ORIGINAL X rows ----------------
__global__ void scatter_kernel(const float* __restrict__ X,
                               const int* __restrict__ idxs,
                               float* __restrict__ dw) {
    int wave = (blockIdx.x * blockDim.x + threadIdx.x) >> 6;
    int lane = threadIdx.x & 63;
    if (wave >= N_PTS) return;
    int idx = idxs[wave];
    const float4* src = (const float4*)(X + (size_t)wave * DIM);
    float* d = dw + (size_t)idx * DIM;
    float4 a = src[lane];
    float4 b = src[lane + 64];
    atomicAdd(d + lane * 4 + 0, a.x);
    atomicAdd(d + lane * 4 + 1, a.y);
    atomicAdd(d + lane * 4 + 2, a.z);
    atomicAdd(d + lane * 4 + 3, a.w);
    atomicAdd(d + 256 + lane * 4 + 0, b.x);
    atomicAdd(d + 256 + lane * 4 + 1, b.y);
    atomicAdd(d + 256 + lane * 4 + 2, b.z);
    atomicAdd(d + 256 + lane * 4 + 3, b.w);
}

// ---------------- new_size (single block) ----------------
__global__ __launch_bounds__(1024) void newsize_kernel(
    const float* __restrict__ ema_size, const int* __restrict__ counts,
    float* __restrict__ out_size) {
    __shared__ float red[16];
    __shared__ float nval;
    int t = threadIdx.x;
    float p0 = ema_size[t] * DECAY + (1.0f - DECAY) * (float)counts[t];
    float p1 = ema_size[t + 1024] * DECAY + (1.0f - DECAY) * (float)counts[t + 1024];
    float s = p0 + p1;
    #pragma unroll
    for (int off = 32; off > 0; off >>= 1) s += __shfl_xor(s, off);
    if ((t & 63) == 0) red[t >> 6] = s;
    __syncthreads();
    if (t == 0) {
        float n = 0.0f;
        for (int i = 0; i < 16; i++) n += red[i];
        nval = n;
    }
    __syncthreads();
    float n = nval;
    float denom = n + (float)N_CLU * EPS;
    out_size[t]        = (p0 + EPS) / denom * n;
    out_size[t + 1024] = (p1 + EPS) / denom * n;
}

// ---------------- new_w, new_centroids ----------------
__global__ void final_kernel(const float* __restrict__ ema_w,
                             const float* __restrict__ dw,
                             const float* __restrict__ new_size,
                             float* __restrict__ out_neww,
                             float* __restrict__ out_newc) {
    int e = blockIdx.x * blockDim.x + threadIdx.x;
    if (e >= N_CLU * DIM) return;
    int k = e >> 9;  // /DIM
    float nw = ema_w[e] * DECAY + (1.0f - DECAY) * dw[e];
    out_neww[e] = nw;
    out_newc[e] = nw / new_size[k];
}

extern "C" void kernel_launch(void* const* d_in, const int* in_sizes, int n_in,
                              void* d_out, int out_size, void* d_ws, size_t ws_size,
                              hipStream_t stream) {
    const float* X        = (const float*)d_in[0];
    const float* C        = (const float*)d_in[1];
    const float* ema_size = (const float*)d_in[2];
    const float* ema_w    = (const float*)d_in[3];
    float* out = (float*)d_out;

    float* out_q    = out + OUT_Q;
    float* out_idx  = out + OUT_IDX;
    float* out_newc = out + OUT_NEWC;
    float* out_sizep= out + OUT_SIZE;
    float* out_neww = out + OUT_NEWW;

    // workspace layout (8B-aligned head)
    char* ws = (char*)d_ws;
    unsigned long long* best = (unsigned long long*)ws;           // 256 KiB
    float* rnorm  = (float*)(ws + N_PTS * 8);                     // 128 KiB
    float* cnorm2 = rnorm + N_PTS;                                // 8 KiB
    int*   idxs   = (int*)(cnorm2 + N_CLU);                       // 128 KiB
    int*   counts = idxs + N_PTS;                                 // 8 KiB
    float* dw     = (float*)(counts + N_CLU);                     // 4 MiB

    init_kernel<<<4096, 256, 0, stream>>>(best, counts, dw);
    rownorm_kernel<<<N_PTS / 4, 256, 0, stream>>>(X, rnorm);
    cnorm_kernel<<<N_CLU / 4, 256, 0, stream>>>(C, cnorm2);

    dim3 grid(N_PTS / BM, N_CLU / BN);
    dist_argmin_kernel<<<grid, 256, 0, stream>>>(X, C, rnorm, cnorm2, best);

    decode_kernel<<<(N_PTS + 255) / 256, 256, 0, stream>>>(best, idxs, out_idx, counts);
    quant_kernel<<<N_PTS / 4, 256, 0, stream>>>(C, idxs, out_q);
    scatter_kernel<<<N_PTS / 4, 256, 0, stream>>>(X, idxs, dw);
    newsize_kernel<<<1, 1024, 0, stream>>>(ema_size, counts, out_sizep);
    final_kernel<<<(N_CLU * DIM) / 256, 256, 0, stream>>>(ema_w, dw, out_sizep, out_neww, out_newc);
}